// Round 2
// baseline (298.652 us; speedup 1.0000x reference)
//
#include <hip/hip_runtime.h>

// ts_zscore: rolling-window z-score
//   x: (B=64, T=4096, F=128) f32 ; out: (B=64, NK=4067, F=128) f32
//   out[b,k,f] = (x[b,k+29,f] - mean(x[b,k:k+30,f])) / (std(...) + 1e-4)

#define B_DIM   64
#define T_DIM   4096
#define F_DIM   128
#define W_WIN   30
#define NK      4067      // T - W + 1 (stride 1, T-w included)
#define CH      128       // output rows per block
#define NCHUNK  32        // ceil(NK / CH)
#define EPS_Z   1e-4f

__global__ __launch_bounds__(64)
void ts_zscore_kernel(const float* __restrict__ x, float* __restrict__ out) {
    // --- bijective XCD swizzle: 2048 blocks, 8 XCDs, 256 contiguous work items per XCD
    int bid = (int)blockIdx.x;
    int cpx = (int)gridDim.x >> 3;            // 2048/8 = 256
    int wid = (bid & 7) * cpx + (bid >> 3);   // adjacent work -> same XCD (L2 halo reuse)

    int b  = wid / NCHUNK;
    int c  = wid % NCHUNK;
    int k0 = c * CH;
    int cnt = NK - k0; if (cnt > CH) cnt = CH;   // 128, or 99 for last chunk

    int lane = (int)threadIdx.x;              // 0..63 ; each lane owns 2 features
    const float2* __restrict__ xp =
        (const float2*)(x + (size_t)b * T_DIM * F_DIM) + (size_t)k0 * 64 + lane;
    float2* __restrict__ op =
        (float2*)(out + (size_t)b * NK * F_DIM) + (size_t)k0 * 64 + lane;

    // --- warm-up: rows k0 .. k0+28 into the register ring; accumulate sums
    float2 ring[29];
    float s1x = 0.f, s1y = 0.f, s2x = 0.f, s2y = 0.f;
    #pragma unroll
    for (int i = 0; i < 29; ++i) {
        float2 v = xp[i * 64];
        ring[i] = v;
        s1x += v.x;       s1y += v.y;
        s2x += v.x * v.x; s2y += v.y * v.y;
    }

    const float inv_w = 1.0f / (float)W_WIN;

    // --- main rolling loop, unrolled by 29 so ring indices are compile-time
    for (int s0 = 0; s0 < cnt; s0 += 29) {
        #pragma unroll
        for (int u = 0; u < 29; ++u) {
            int ss = s0 + u;                 // wave-uniform guard, no divergence
            if (ss < cnt) {
                float2 v = xp[(29 + ss) * 64];          // newest row k0+ss+29 (== "last")
                float t1x = s1x + v.x,        t1y = s1y + v.y;
                float t2x = s2x + v.x * v.x,  t2y = s2y + v.y * v.y;

                float mx = t1x * inv_w,  my = t1y * inv_w;
                float vx = fmaxf(t2x * inv_w - mx * mx, 0.f);
                float vy = fmaxf(t2y * inv_w - my * my, 0.f);
                float ox = (v.x - mx) / (sqrtf(vx) + EPS_Z);
                float oy = (v.y - my) / (sqrtf(vy) + EPS_Z);
                op[ss * 64] = make_float2(ox, oy);

                float2 old = ring[u];                   // oldest row k0+ss
                s1x = t1x - old.x;         s1y = t1y - old.y;
                s2x = t2x - old.x * old.x; s2y = t2y - old.y * old.y;
                ring[u] = v;                            // reused at step ss+29
            }
        }
    }
}

extern "C" void kernel_launch(void* const* d_in, const int* in_sizes, int n_in,
                              void* d_out, int out_size, void* d_ws, size_t ws_size,
                              hipStream_t stream) {
    const float* x = (const float*)d_in[0];
    float* out = (float*)d_out;
    dim3 grid(B_DIM * NCHUNK);   // 2048 blocks
    dim3 block(64);              // one wave per block
    ts_zscore_kernel<<<grid, block, 0, stream>>>(x, out);
}

// Round 3
// 257.962 us; speedup vs baseline: 1.1577x; 1.1577x over previous
//
#include <hip/hip_runtime.h>

// ts_zscore: rolling-window z-score
//   x: (B=64, T=4096, F=128) f32 ; out: (B=64, NK=4067, F=128) f32
//   out[b,k,f] = (x[b,k+29,f] - mean(x[b,k:k+30,f])) / (std(...) + 1e-4)
//
// R3: occupancy fix. R2 was latency-bound (occ 20.8%, 1.5 TB/s, VALUBusy 23%).
// 4 waves/block, one 64-row chunk per wave -> 4096 waves (16/CU, ~50% occ).
// Ring buffer dropped: compiler was re-loading the old row anyway (VGPR=44);
// we re-load it explicitly (L1/L2-hot, touched 29 steps earlier).

#define B_DIM   64
#define T_DIM   4096
#define F_DIM   128
#define W_WIN   30
#define NK      4067      // T - W + 1 (stride 1, T-w included)
#define CH      64        // output rows per wave-chunk
#define CPB     64        // chunks per batch = ceil(NK/CH)
#define EPS_Z   1e-4f

__global__ __launch_bounds__(256)
void ts_zscore_kernel(const float* __restrict__ x, float* __restrict__ out) {
    // bijective XCD swizzle: 1024 blocks, 8 XCDs, 128 contiguous blocks per XCD
    int bid = (int)blockIdx.x;
    int cpx = (int)gridDim.x >> 3;            // 1024/8 = 128
    int swz = (bid & 7) * cpx + (bid >> 3);   // adjacent chunks -> same XCD (halo L2 reuse)

    int wave = (int)threadIdx.x >> 6;
    int lane = (int)threadIdx.x & 63;         // each lane owns 2 features (float2)

    int g  = swz * 4 + wave;                  // global chunk id, 0..4095
    int b  = g >> 6;                          // / CPB
    int c  = g & (CPB - 1);
    int k0 = c * CH;
    int cnt = NK - k0; if (cnt > CH) cnt = CH;   // 64, or 35 for last chunk

    const float2* __restrict__ xp =
        (const float2*)(x + (size_t)b * T_DIM * F_DIM) + (size_t)k0 * 64 + lane;
    float2* __restrict__ op =
        (float2*)(out + (size_t)b * NK * F_DIM) + (size_t)k0 * 64 + lane;

    // warm-up: sums over rows k0 .. k0+28 (29 rows)
    float s1x = 0.f, s1y = 0.f, s2x = 0.f, s2y = 0.f;
    #pragma unroll
    for (int i = 0; i < 29; ++i) {
        float2 v = xp[i * 64];
        s1x += v.x;       s1y += v.y;
        s2x += v.x * v.x; s2y += v.y * v.y;
    }

    const float inv_w = 1.0f / (float)W_WIN;

    #pragma unroll 8
    for (int ss = 0; ss < cnt; ++ss) {
        float2 v = xp[(29 + ss) * 64];        // newest row (== "last"), streams from HBM/L3
        float2 o = xp[ss * 64];               // oldest row, L1/L2-hot (read 29 steps ago)

        float t1x = s1x + v.x,        t1y = s1y + v.y;
        float t2x = s2x + v.x * v.x,  t2y = s2y + v.y * v.y;

        float mx = t1x * inv_w,  my = t1y * inv_w;
        float vx = fmaxf(t2x * inv_w - mx * mx, 0.f);
        float vy = fmaxf(t2y * inv_w - my * my, 0.f);
        float ox = (v.x - mx) / (sqrtf(vx) + EPS_Z);
        float oy = (v.y - my) / (sqrtf(vy) + EPS_Z);
        op[ss * 64] = make_float2(ox, oy);

        s1x = t1x - o.x;         s1y = t1y - o.y;
        s2x = t2x - o.x * o.x;   s2y = t2y - o.y * o.y;
    }
}

extern "C" void kernel_launch(void* const* d_in, const int* in_sizes, int n_in,
                              void* d_out, int out_size, void* d_ws, size_t ws_size,
                              hipStream_t stream) {
    const float* x = (const float*)d_in[0];
    float* out = (float*)d_out;
    dim3 grid((B_DIM * CPB) / 4);   // 1024 blocks of 4 waves, one chunk per wave
    dim3 block(256);
    ts_zscore_kernel<<<grid, block, 0, stream>>>(x, out);
}